// Round 6
// baseline (219.078 us; speedup 1.0000x reference)
//
#include <hip/hip_runtime.h>

// BatchBlur via bf16 MFMA banded-Toeplitz. R10: best-of-measured combo.
// Evidence base: dur tracks hbm_bytes/2.5TB/s across R5-R9; TW=128 measured
// lowest bytes (FETCH 80.7 vs 94.2 MB at TW=64). R9's per-ky GLOBAL A-frag
// chain (1-deep, 200-500cyc) serialized the ky loop -> A-frags (identical
// across all 4 waves of a block!) now bulk-copied to LDS once per block.
//  - TW=128/TH=64, SWB=152 (R6 config, known-good; ~1920 conflict-cyc/block)
//  - sa: ws A-frags (15360B) copied global->reg->LDS during staging;
//    per-ky A = one conflict-free ds_read_b128, 1-deep register prefetch
//  - aligned 16B staging (slab col0 <-> ox0-8); band = K[ky][k-m-1]
//    (prep kernel unchanged from R9); slab cols 0/144.. hit only zero coeffs
//  - LDS 39072B -> 4 blocks/CU, __launch_bounds__(256,4): 128-VGPR budget,
//    vv[13][4] live set fits without spills
// Layouts (verified): A: m=lane&15,k=q*8+j ; B: n=lane&15,k=q*8+j ;
// D: n=lane&15, m=q*4+reg.

#define HH 512
#define WW 512
#define LL 15
#define PP 7
#define TW 128
#define TH 64
#define SH (TH + LL - 1)          // 78
#define SWB 152                   // slab row in bf16 elems; 304B rows
#define KPAD 64                   // fallback kernel row pad
#define NSEG 8
#define NRS 6                     // row-starts in staging
#define NROWIT 13                 // 78 / 6
#define AFRAG_BYTES (32 * LL * 64 * 16)   // 491520

typedef __attribute__((ext_vector_type(8))) short bf16x8;
typedef __attribute__((ext_vector_type(4))) float f32x4;

__device__ inline unsigned short f2bf(float f) {
    unsigned u = __builtin_bit_cast(unsigned, f);
    return (unsigned short)((u + 0x7fffu + ((u >> 16) & 1u)) >> 16);   // RNE
}

__device__ inline unsigned cvt_pk_bf16(float lo, float hi) {
    unsigned r;
    asm("v_cvt_pk_bf16_f32 %0, %1, %2" : "=v"(r) : "v"(lo), "v"(hi));
    return r;
}

// ---- prep: ws[((b*LL+ky)*64+lane)] = 16B A-fragment, A[j]=K[ky][q*8+j-t-1]
__global__ void prep_afrags(const float* __restrict__ kern,
                            unsigned short* __restrict__ ws)
{
    const int b    = blockIdx.x;
    const int lane = threadIdx.x & 63;
    const int t    = lane & 15;
    const int q    = lane >> 4;
    const float* __restrict__ kp = kern + b * (LL * LL);
    for (int ky = 0; ky < LL; ++ky) {
        unsigned pk[4];
        #pragma unroll
        for (int d = 0; d < 4; ++d) {
            unsigned short h[2];
            #pragma unroll
            for (int u = 0; u < 2; ++u) {
                int idx = q * 8 + 2 * d + u - t - 1;
                float v = (idx >= 0 && idx < LL) ? kp[ky * LL + idx] : 0.f;
                h[u] = f2bf(v);
            }
            pk[d] = (unsigned)h[0] | ((unsigned)h[1] << 16);
        }
        *(uint4*)&ws[((size_t)(b * LL + ky) * 64 + lane) * 8] =
            make_uint4(pk[0], pk[1], pk[2], pk[3]);
    }
}

// Fallback A-build (no ws): elements e..e+7 of zero-padded kernel row ky.
__device__ __forceinline__ bf16x8 abuild(const unsigned short* sk, int ky,
                                         int base, int sh) {
    const int* rp = (const int*)&sk[ky * KPAD];
    int v0 = rp[base], v1 = rp[base + 1], v2 = rp[base + 2],
        v3 = rp[base + 3], v4 = rp[base + 4];
    int r0 = (int)(unsigned)((((unsigned long long)(unsigned)v1 << 32) | (unsigned)v0) >> sh);
    int r1 = (int)(unsigned)((((unsigned long long)(unsigned)v2 << 32) | (unsigned)v1) >> sh);
    int r2 = (int)(unsigned)((((unsigned long long)(unsigned)v3 << 32) | (unsigned)v2) >> sh);
    int r3 = (int)(unsigned)((((unsigned long long)(unsigned)v4 << 32) | (unsigned)v3) >> sh);
    return __builtin_bit_cast(bf16x8, (int4){r0, r1, r2, r3});
}

template<int USE_WS>
__global__ __launch_bounds__(256, 4)
void batchblur_mfma(const float* __restrict__ x,
                    const float* __restrict__ kern,
                    const unsigned short* __restrict__ af,
                    float* __restrict__ out)
{
    __shared__ unsigned short sx[SH * SWB];   // 23712 B
    __shared__ uint4 sa4[LL * 64];            // 15360 B (ws path only)
    __shared__ unsigned short sk[LL * KPAD];  // 1920 B (fallback path only)

    const int tid   = threadIdx.x;
    const int ox0   = blockIdx.x * TW;
    const int oy0   = blockIdx.y * TH;
    const int plane = blockIdx.z;
    const int b     = plane / 3;

    const float* __restrict__ xp = x + (size_t)plane * (HH * WW);

    // ---- phase 1a: issue A-frag bulk-copy loads (L2/L3-hot, 15360B/block) ----
    uint4 av[4];
    if constexpr (USE_WS) {
        const uint4* __restrict__ afb = (const uint4*)af + (size_t)b * (LL * 64);
        #pragma unroll
        for (int it = 0; it < 4; ++it) {
            int i = tid + it * 256;
            if (i < LL * 64) av[it] = afb[i];
        }
    }

    // ---- phase 1b: issue ALL slab loads (16B-aligned) ----
    // 228 active threads = 38 col-quads x 6 row-starts; 13 rows each.
    const bool act = tid < 228;
    int r0 = 0, c4 = 0;
    float vv[NROWIT][4];
    if (act) {
        r0 = tid / 38;                 // 0..5
        c4 = (tid - r0 * 38) * 4;      // 0..148
        const int gbase = ox0 + c4 - 8;                      // multiple of 4
        const bool vec = (gbase >= 0) && (gbase + 3 < WW);   // no x-reflection
        int gx[4];
        if (!vec) {
            #pragma unroll
            for (int j = 0; j < 4; ++j) {
                int g = gbase + j;
                gx[j] = g < 0 ? -g : (g >= WW ? 2 * WW - 2 - g : g);
            }
        }
        #pragma unroll
        for (int k = 0; k < NROWIT; ++k) {
            int gy = oy0 + (r0 + NRS * k) - PP;
            gy = gy < 0 ? -gy : (gy >= HH ? 2 * HH - 2 - gy : gy);
            const float* __restrict__ rowp = xp + (size_t)gy * WW;
            if (vec) {
                float4 v = *(const float4*)(rowp + gbase);   // aligned 16B
                vv[k][0] = v.x; vv[k][1] = v.y; vv[k][2] = v.z; vv[k][3] = v.w;
            } else {
                #pragma unroll
                for (int j = 0; j < 4; ++j) vv[k][j] = rowp[gx[j]];
            }
        }
    }

    if constexpr (!USE_WS) {
        // fallback: stage zero-padded kernel rows while slab loads fly
        const float* __restrict__ kp = kern + b * (LL * LL);
        for (int i = tid; i < LL * KPAD; i += 256) {
            int ky = i >> 6, c = i & 63;
            float v = (c >= 16 && c < 16 + LL) ? kp[ky * LL + (c - 16)] : 0.f;
            sk[i] = f2bf(v);
        }
    }

    // ---- phase 2a: A-frags -> LDS (waits only on the early sa loads) ----
    if constexpr (USE_WS) {
        #pragma unroll
        for (int it = 0; it < 4; ++it) {
            int i = tid + it * 256;
            if (i < LL * 64) sa4[i] = av[it];
        }
    }

    // ---- phase 2b: slab convert (packed RNE) + ds_write_b64 ----
    if (act) {
        #pragma unroll
        for (int k = 0; k < NROWIT; ++k) {
            int r = r0 + NRS * k;
            uint2 pk;
            pk.x = cvt_pk_bf16(vv[k][0], vv[k][1]);
            pk.y = cvt_pk_bf16(vv[k][2], vv[k][3]);
            *(uint2*)&sx[r * SWB + c4] = pk;
        }
    }
    __syncthreads();

    const int lane = tid & 63;
    const int t    = lane & 15;       // A row m / B-D col n
    const int q    = lane >> 4;       // quad
    const int g    = tid >> 6;        // wave -> 16-row group
    const int rowbase = g * 16 + t;

    f32x4 acc[NSEG];
    #pragma unroll
    for (int s = 0; s < NSEG; ++s) acc[s] = (f32x4){0.f, 0.f, 0.f, 0.f};

    if constexpr (USE_WS) {
        uint4 a_nxt = sa4[lane];      // ky = 0
        #pragma unroll 1
        for (int ky = 0; ky < LL; ++ky) {
            bf16x8 afrag = __builtin_bit_cast(bf16x8, a_nxt);
            if (ky < LL - 1) a_nxt = sa4[(ky + 1) * 64 + lane];   // LDS prefetch
            const unsigned short* srow = &sx[(rowbase + ky) * SWB + q * 8];
            bf16x8 bf[4];
            #pragma unroll
            for (int s = 0; s < 4; ++s) bf[s] = *(const bf16x8*)&srow[s * 16];
            #pragma unroll
            for (int s = 0; s < 4; ++s)
                acc[s] = __builtin_amdgcn_mfma_f32_16x16x32_bf16(afrag, bf[s], acc[s], 0, 0, 0);
            #pragma unroll
            for (int s = 0; s < 4; ++s) bf[s] = *(const bf16x8*)&srow[(s + 4) * 16];
            #pragma unroll
            for (int s = 0; s < 4; ++s)
                acc[s + 4] = __builtin_amdgcn_mfma_f32_16x16x32_bf16(afrag, bf[s], acc[s + 4], 0, 0, 0);
        }
    } else {
        // A-band for the -8-shifted slab: A[m][k] = K[ky][k-m-1],
        // window start e = 15 + q*8 - t in padded row (pad K at c=16..30).
        const int e    = 15 + q * 8 - t;  // in [0, 39]
        const int b0   = 2 * e;           // in [0, 78]
        const int base = b0 >> 2;         // dword index <= 19; base+4 <= 23 < 32
        const int sh   = (b0 & 3) * 8;    // 0 or 16
        #pragma unroll 1
        for (int ky = 0; ky < LL; ++ky) {
            bf16x8 afrag = abuild(sk, ky, base, sh);
            const unsigned short* srow = &sx[(rowbase + ky) * SWB + q * 8];
            bf16x8 bf[4];
            #pragma unroll
            for (int s = 0; s < 4; ++s) bf[s] = *(const bf16x8*)&srow[s * 16];
            #pragma unroll
            for (int s = 0; s < 4; ++s)
                acc[s] = __builtin_amdgcn_mfma_f32_16x16x32_bf16(afrag, bf[s], acc[s], 0, 0, 0);
            #pragma unroll
            for (int s = 0; s < 4; ++s) bf[s] = *(const bf16x8*)&srow[(s + 4) * 16];
            #pragma unroll
            for (int s = 0; s < 4; ++s)
                acc[s + 4] = __builtin_amdgcn_mfma_f32_16x16x32_bf16(afrag, bf[s], acc[s + 4], 0, 0, 0);
        }
    }

    // ---- store: 8 x float4, D layout n=lane&15 (row), m=q*4+reg (col) ----
    float* __restrict__ op = out + (size_t)plane * (HH * WW) + (size_t)(oy0 + rowbase) * WW + ox0;
    #pragma unroll
    for (int s = 0; s < NSEG; ++s) {
        float* dst = op + s * 16 + q * 4;
        *(float4*)dst = make_float4(acc[s][0], acc[s][1], acc[s][2], acc[s][3]);
    }
}

extern "C" void kernel_launch(void* const* d_in, const int* in_sizes, int n_in,
                              void* d_out, int out_size, void* d_ws, size_t ws_size,
                              hipStream_t stream) {
    const float* x  = (const float*)d_in[0];
    const float* kn = (const float*)d_in[1];
    float* out      = (float*)d_out;
    dim3 grid(WW / TW, HH / TH, 32 * 3);   // (4, 8, 96)
    const bool use_ws = (d_ws != nullptr) && (ws_size >= (size_t)AFRAG_BYTES);
    if (use_ws) {
        prep_afrags<<<dim3(32), dim3(64), 0, stream>>>(kn, (unsigned short*)d_ws);
        batchblur_mfma<1><<<grid, dim3(256), 0, stream>>>(x, kn, (const unsigned short*)d_ws, out);
    } else {
        batchblur_mfma<0><<<grid, dim3(256), 0, stream>>>(x, kn, nullptr, out);
    }
}

// Round 8
// 201.940 us; speedup vs baseline: 1.0849x; 1.0849x over previous
//
#include <hip/hip_runtime.h>

// BatchBlur via bf16 MFMA banded-Toeplitz. R12 = R11 with the A-band
// off-by-one FIXED: R11 paired the -8-shifted slab (col c <-> ox0+c-8) with
// the unshifted band K[k-m]. Correct pairing: padded[c]=K[c-16] (c>=16, as
// in passing R6) + e = 15+q*8-t  ==>  A[m][k] = padded[15+k-m] = K[k-m-1].
// (R6 sanity: shift 0, pad 16, e=16 -> K[k-m]; both derivations consistent.)
// Structure (from R11): R6 base (TW=128, SWB=152, in-kernel A-build) +
// vertical 2-tile pipeline per block:
//  - 128x128 output region/block; 78-row circular slab, slot=(row+7+p-Y) mod 78
//  - tile1's 64 rows ISSUED right after first barrier -> latency hides under
//    tile0's MFMA loop; converted+written after post-compute barrier (T14)
//  - saves one stage-latency exposure per 2 tiles + 9% vertical halo
//    (142 rows/pair vs 156)
//  - 16B-aligned staging (slab col0 <-> ox0-8)
//  - launch_bounds(256,5). Tripwire: WRITE_SIZE != 98304 KB => scratch spill.
// Layouts (verified): A: m=lane&15,k=q*8+j ; B: n=lane&15,k=q*8+j ;
// D: n=lane&15, m=q*4+reg.

#define HH 512
#define WW 512
#define LL 15
#define PP 7
#define TW 128
#define TH 64
#define SH (TH + LL - 1)          // 78 (circular slab rows)
#define SWB 152                   // slab row in bf16 elems; 304B rows
#define KPAD 64                   // kernel row pad (128B)
#define NSEG 8
#define NRS 6                     // row-starts in staging (228 = 38x6 threads)
#define NROWIT0 13                // ceil(78/6)
#define NROWIT1 11                // ceil(64/6)

typedef __attribute__((ext_vector_type(8))) short bf16x8;
typedef __attribute__((ext_vector_type(4))) float f32x4;

__device__ inline unsigned short f2bf(float f) {
    unsigned u = __builtin_bit_cast(unsigned, f);
    return (unsigned short)((u + 0x7fffu + ((u >> 16) & 1u)) >> 16);   // RNE
}

__device__ inline unsigned cvt_pk_bf16(float lo, float hi) {
    unsigned r;
    asm("v_cvt_pk_bf16_f32 %0, %1, %2" : "=v"(r) : "v"(lo), "v"(hi));
    return r;
}

__device__ inline int reflect_y(int p) {
    return p < 0 ? -p : (p >= HH ? 2 * HH - 2 - p : p);
}

// Banded A fragment: padded-row elements e..e+7 (padded[c]=K[c-16]), via five
// 4B-aligned LDS dwords + 32-bit funnel shifts (sh in {0,16}).
__device__ __forceinline__ bf16x8 abuild(const unsigned short* sk, int ky,
                                         int base, int sh) {
    const int* rp = (const int*)&sk[ky * KPAD];
    int v0 = rp[base], v1 = rp[base + 1], v2 = rp[base + 2],
        v3 = rp[base + 3], v4 = rp[base + 4];
    int r0 = (int)(unsigned)((((unsigned long long)(unsigned)v1 << 32) | (unsigned)v0) >> sh);
    int r1 = (int)(unsigned)((((unsigned long long)(unsigned)v2 << 32) | (unsigned)v1) >> sh);
    int r2 = (int)(unsigned)((((unsigned long long)(unsigned)v3 << 32) | (unsigned)v2) >> sh);
    int r3 = (int)(unsigned)((((unsigned long long)(unsigned)v4 << 32) | (unsigned)v3) >> sh);
    return __builtin_bit_cast(bf16x8, (int4){r0, r1, r2, r3});
}

__global__ __launch_bounds__(256, 5)
void batchblur_mfma(const float* __restrict__ x,
                    const float* __restrict__ kern,
                    float* __restrict__ out)
{
    __shared__ unsigned short sx[SH * SWB];   // 23712 B (circular)
    __shared__ unsigned short sk[LL * KPAD];  // 1920 B

    const int tid   = threadIdx.x;
    const int ox0   = blockIdx.x * TW;
    const int Y     = blockIdx.y * (2 * TH);  // y-tile pair base row
    const int plane = blockIdx.z;
    const int b     = plane / 3;

    const float* __restrict__ xp = x + (size_t)plane * (HH * WW);
    const float* __restrict__ kp = kern + b * (LL * LL);

    // ---- staging geometry: 228 threads = 38 col-quads x 6 row-starts ----
    const bool act = tid < 228;
    int r0 = 0, c4 = 0, gbase = 0;
    bool vec = false;
    int gx[4];
    float vv[NROWIT0][4];
    if (act) {
        r0 = tid / 38;                 // 0..5
        c4 = (tid - r0 * 38) * 4;      // 0..148
        gbase = ox0 + c4 - 8;          // multiple of 4 -> aligned float4
        vec = (gbase >= 0) && (gbase + 3 < WW);
        if (!vec) {
            #pragma unroll
            for (int j = 0; j < 4; ++j) {
                int g = gbase + j;
                gx[j] = g < 0 ? -g : (g >= WW ? 2 * WW - 2 - g : g);
            }
        }
        // ---- tile0: issue loads for slab rows p = Y-7 .. Y+70 (slots 0..77)
        #pragma unroll
        for (int k = 0; k < NROWIT0; ++k) {
            int gy = reflect_y(Y + (r0 + NRS * k) - PP);
            const float* __restrict__ rowp = xp + (size_t)gy * WW;
            if (vec) {
                float4 v = *(const float4*)(rowp + gbase);
                vv[k][0] = v.x; vv[k][1] = v.y; vv[k][2] = v.z; vv[k][3] = v.w;
            } else {
                #pragma unroll
                for (int j = 0; j < 4; ++j) vv[k][j] = rowp[gx[j]];
            }
        }
    }

    // ---- stage zero-padded kernel rows (padded[c]=K[c-16]) while loads fly
    for (int i = tid; i < LL * KPAD; i += 256) {
        int ky = i >> 6, c = i & 63;
        float v = (c >= 16 && c < 16 + LL) ? kp[ky * LL + (c - 16)] : 0.f;
        sk[i] = f2bf(v);
    }

    // ---- tile0 convert + LDS write ----
    if (act) {
        #pragma unroll
        for (int k = 0; k < NROWIT0; ++k) {
            int r = r0 + NRS * k;
            uint2 pk;
            pk.x = cvt_pk_bf16(vv[k][0], vv[k][1]);
            pk.y = cvt_pk_bf16(vv[k][2], vv[k][3]);
            *(uint2*)&sx[r * SWB + c4] = pk;
        }
    }
    __syncthreads();

    // ---- issue tile1's loads NOW: rows p = Y+71 .. Y+134 -> slots 0..63.
    // They fly under tile0's entire MFMA loop (write happens after barrier).
    if (act) {
        #pragma unroll
        for (int k = 0; k < NROWIT1; ++k) {
            int r = r0 + NRS * k;
            if (r < TH) {
                int gy = reflect_y(Y + 71 + r);
                const float* __restrict__ rowp = xp + (size_t)gy * WW;
                if (vec) {
                    float4 v = *(const float4*)(rowp + gbase);
                    vv[k][0] = v.x; vv[k][1] = v.y; vv[k][2] = v.z; vv[k][3] = v.w;
                } else {
                    #pragma unroll
                    for (int j = 0; j < 4; ++j) vv[k][j] = rowp[gx[j]];
                }
            }
        }
    }

    const int lane = tid & 63;
    const int t    = lane & 15;       // A row m / B-D col n
    const int q    = lane >> 4;       // quad
    const int g    = tid >> 6;        // wave -> 16-row group
    const int rowbase = g * 16 + t;

    // A-band geometry (loop-invariant): e = 15 + q*8 - t, padded[c]=K[c-16]
    // ==> A[m][k] = padded[15+k-m] = K[k-m-1]  (matches the -8 slab shift).
    const int e    = 15 + q * 8 - t;  // in [0, 39]
    const int b0   = 2 * e;           // in [0, 78]
    const int base = b0 >> 2;         // dword index <= 19; base+4 <= 23 < 32
    const int sh   = (b0 & 3) * 8;    // 0 or 16

    f32x4 acc[NSEG];
    #pragma unroll
    for (int s = 0; s < NSEG; ++s) acc[s] = (f32x4){0.f, 0.f, 0.f, 0.f};

    // ---- tile0 compute: slab slot = rowbase + ky (no wrap) ----
    #pragma unroll 1
    for (int ky = 0; ky < LL; ++ky) {
        bf16x8 afrag = abuild(sk, ky, base, sh);
        const unsigned short* srow = &sx[(rowbase + ky) * SWB + q * 8];
        bf16x8 bf[4];
        #pragma unroll
        for (int s = 0; s < 4; ++s) bf[s] = *(const bf16x8*)&srow[s * 16];
        #pragma unroll
        for (int s = 0; s < 4; ++s)
            acc[s] = __builtin_amdgcn_mfma_f32_16x16x32_bf16(afrag, bf[s], acc[s], 0, 0, 0);
        #pragma unroll
        for (int s = 0; s < 4; ++s) bf[s] = *(const bf16x8*)&srow[(s + 4) * 16];
        #pragma unroll
        for (int s = 0; s < 4; ++s)
            acc[s + 4] = __builtin_amdgcn_mfma_f32_16x16x32_bf16(afrag, bf[s], acc[s + 4], 0, 0, 0);
    }

    // ---- store tile0 ----
    {
        float* __restrict__ op = out + (size_t)plane * (HH * WW)
                               + (size_t)(Y + rowbase) * WW + ox0;
        #pragma unroll
        for (int s = 0; s < NSEG; ++s) {
            float* dst = op + s * 16 + q * 4;
            *(float4*)dst = make_float4(acc[s][0], acc[s][1], acc[s][2], acc[s][3]);
        }
    }

    __syncthreads();   // all waves done reading slots 0..63 of tile0

    // ---- tile1 convert + LDS write (loads have long arrived) ----
    if (act) {
        #pragma unroll
        for (int k = 0; k < NROWIT1; ++k) {
            int r = r0 + NRS * k;
            if (r < TH) {
                uint2 pk;
                pk.x = cvt_pk_bf16(vv[k][0], vv[k][1]);
                pk.y = cvt_pk_bf16(vv[k][2], vv[k][3]);
                *(uint2*)&sx[r * SWB + c4] = pk;
            }
        }
    }
    __syncthreads();

    #pragma unroll
    for (int s = 0; s < NSEG; ++s) acc[s] = (f32x4){0.f, 0.f, 0.f, 0.f};

    // ---- tile1 compute: slab slot = (64 + rowbase + ky) mod 78 ----
    #pragma unroll 1
    for (int ky = 0; ky < LL; ++ky) {
        bf16x8 afrag = abuild(sk, ky, base, sh);
        int slot = 64 + rowbase + ky;
        if (slot >= SH) slot -= SH;
        const unsigned short* srow = &sx[slot * SWB + q * 8];
        bf16x8 bf[4];
        #pragma unroll
        for (int s = 0; s < 4; ++s) bf[s] = *(const bf16x8*)&srow[s * 16];
        #pragma unroll
        for (int s = 0; s < 4; ++s)
            acc[s] = __builtin_amdgcn_mfma_f32_16x16x32_bf16(afrag, bf[s], acc[s], 0, 0, 0);
        #pragma unroll
        for (int s = 0; s < 4; ++s) bf[s] = *(const bf16x8*)&srow[(s + 4) * 16];
        #pragma unroll
        for (int s = 0; s < 4; ++s)
            acc[s + 4] = __builtin_amdgcn_mfma_f32_16x16x32_bf16(afrag, bf[s], acc[s + 4], 0, 0, 0);
    }

    // ---- store tile1 ----
    {
        float* __restrict__ op = out + (size_t)plane * (HH * WW)
                               + (size_t)(Y + TH + rowbase) * WW + ox0;
        #pragma unroll
        for (int s = 0; s < NSEG; ++s) {
            float* dst = op + s * 16 + q * 4;
            *(float4*)dst = make_float4(acc[s][0], acc[s][1], acc[s][2], acc[s][3]);
        }
    }
}

extern "C" void kernel_launch(void* const* d_in, const int* in_sizes, int n_in,
                              void* d_out, int out_size, void* d_ws, size_t ws_size,
                              hipStream_t stream) {
    const float* x  = (const float*)d_in[0];
    const float* kn = (const float*)d_in[1];
    float* out      = (float*)d_out;
    dim3 grid(WW / TW, HH / (2 * TH), 32 * 3);   // (4, 4, 96)
    batchblur_mfma<<<grid, dim3(256), 0, stream>>>(x, kn, out);
}